// Round 3
// baseline (319.004 us; speedup 1.0000x reference)
//
#include <hip/hip_runtime.h>
#include <hip/hip_bf16.h>
#include <stdint.h>

// Per-edge MLP  out = relu(relu([h[src],h[dst]] @ W1.T + b1) @ W2.T + b2) @ W3.T + b3
// N=100000, H=128, E=1.6M, layers 256->64->32->6, fp32 in/out.
//
// R11: edge_mlp restructured for latency hiding. R9 post-mortem: VALU cut
// 1.5x (VALUBusy 50->34%) with ZERO duration change => edge_mlp is
// memory-latency-bound (~4000 stall cyc/wave), all throughput pipes <41%.
// Changes:
//  - 128 edges/wave (was 64): 32 gathers in flight per wave, half the waves,
//    half the per-wave prologue overhead. ~200 VGPR (<256 => 8 waves/SIMD ok).
//  - LDS eliminated: layer-2 -> layer-3 redistribution is a permutation among
//    the 4 lanes sharing m15 => 8 ds_bpermute + 4 cndmask per subtile replaces
//    the z-slab (kills 1.2M bank-conflict cycles, LDS_Block_Size -> 0, no
//    LDS cap on blocks/CU).
// node_gemm / prep_weights unchanged from R9 (passed, absmax 0.00195).
//
// MFMA 16x16x32_bf16 layouts (m89/m91-verified):
//   A[m=lane&15][k=(lane>>4)*8+j], B[k=(lane>>4)*8+j][n=lane&15],
//   C/D: col=lane&15, row=(lane>>4)*4+reg.  A- and B-frag lane maps are the
//   same pattern, so mfma(W,X) vs mfma(X,W) transposes D for free.
// Layer-3 redistribution map (derived & element-checked):
//   source lane (quad',m15) holds z[edge=m15][chan=nt*16+quad'*4+r] as packed
//   pairs pk[nt][0]=chans{+0,+1}, pk[nt][1]=chans{+2,+3}.
//   target lane (q,m15) needs A3 = chans q*8..q*8+7 of edge m15:
//     dwords 0,1 <- lane ((q&1)*2)*16+m15   pk[q>>1][0..1]
//     dwords 2,3 <- lane ((q&1)*2+1)*16+m15 pk[q>>1][0..1]

#define H 128

typedef short bf16x8 __attribute__((ext_vector_type(8)));
typedef float f32x4  __attribute__((ext_vector_type(4)));

__device__ __forceinline__ uint16_t f2bf(float f) {           // RNE fp32->bf16 (prep only)
    uint32_t u = __float_as_uint(f);
    return (uint16_t)((u + 0x7fffu + ((u >> 16) & 1u)) >> 16);
}

// HW RNE pack of two f32 into packed bf16 (1 VALU inst; no builtin on gfx950).
__device__ __forceinline__ uint32_t cvtpk(float lo, float hi) {
    uint32_t r;
    asm("v_cvt_pk_bf16_f32 %0, %1, %2" : "=v"(r) : "v"(lo), "v"(hi));
    return r;
}

// relu(a+b) on a packed bf16 pair: exact unpack via shifts, f32 math, HW RNE pack.
__device__ __forceinline__ uint32_t bfadd2_relu(uint32_t a, uint32_t b) {
    float alo = __uint_as_float(a << 16);
    float ahi = __uint_as_float(a & 0xffff0000u);
    float blo = __uint_as_float(b << 16);
    float bhi = __uint_as_float(b & 0xffff0000u);
    float slo = fmaxf(alo + blo, 0.f);
    float shi = fmaxf(ahi + bhi, 0.f);
    return cvtpk(slo, shi);
}

// ---------------- weight prep (unchanged) ------------------------------------
// Bfrag: concat-W1, 4 ktiles x 8 tiles (32 KB):
//   i = ((kt*8+ct)*64+lane)*8+j -> W1cat[n=ct*16+(lane&15)][k=kt*32+(lane>>4)*8+j]
// EFrag: 5 frags x 64 lanes x 8 bf16 (5 KB): W2 (4 frags) + W3 zero-padded.
__global__ void prep_weights(const float* __restrict__ W1,
                             const float* __restrict__ W2,
                             const float* __restrict__ W3,
                             uint16_t* __restrict__ Bfrag,
                             uint16_t* __restrict__ EFrag)
{
    int t = blockIdx.x * blockDim.x + threadIdx.x;
    int stride = gridDim.x * blockDim.x;
    for (int i = t; i < 4 * 8 * 64 * 8; i += stride) {
        int j    = i & 7;
        int lane = (i >> 3) & 63;
        int nt   = (i >> 9) & 7;
        int kt   = (i >> 12);
        int k = kt * 32 + (lane >> 4) * 8 + j;
        int n = nt * 16 + (lane & 15);
        float v = (n < 64) ? W1[n * 256 + k] : W1[(n - 64) * 256 + 128 + k];
        Bfrag[i] = f2bf(v);
    }
    for (int i = t; i < 5 * 64 * 8; i += stride) {
        int j    = i & 7;
        int lane = (i >> 3) & 63;
        int f    = i >> 9;
        uint16_t v;
        if (f < 4) {
            int kt = f >> 1, nt = f & 1;
            int k = kt * 32 + (lane >> 4) * 8 + j;
            int n = nt * 16 + (lane & 15);
            v = f2bf(W2[n * 64 + k]);
        } else {
            int k = (lane >> 4) * 8 + j;
            int n = lane & 15;
            v = (n < 6) ? f2bf(W3[n * 32 + k]) : (uint16_t)0;
        }
        EFrag[i] = v;
    }
}

// ---------------- per-node precompute: pre = h @ concat-W1 (+b1), MFMA ------
// Operand-swapped: D[m=chan][n=node] = mfma(A=W1frag, B=hfrag). Unchanged.
__global__ void __launch_bounds__(256) node_gemm(
    const float* __restrict__ h,
    const uint16_t* __restrict__ Bfrag,
    const float* __restrict__ b1,
    uint16_t* __restrict__ pre, int N)
{
    const int wave = threadIdx.x >> 6;
    const int lane = threadIdx.x & 63;
    const int n0 = (blockIdx.x * 4 + wave) * 32;
    if (n0 >= N) return;

    const int m15  = lane & 15;
    const int quad = lane >> 4;

    // B-fragments from h rows: B[k=kt*32+quad*8+j][node=m15] (fp32->bf16 RNE).
    bf16x8 hb[2][4];
#pragma unroll
    for (int t = 0; t < 2; t++) {
        int row = n0 + t * 16 + m15; if (row >= N) row = N - 1;   // stores guarded
        const float* hrow = h + (size_t)row * H + quad * 8;
#pragma unroll
        for (int kt = 0; kt < 4; kt++) {
            float4 lo = *(const float4*)(hrow + kt * 32);
            float4 hi = *(const float4*)(hrow + kt * 32 + 4);
            union { bf16x8 v; uint32_t u[4]; } B;
            B.u[0] = cvtpk(lo.x, lo.y); B.u[1] = cvtpk(lo.z, lo.w);
            B.u[2] = cvtpk(hi.x, hi.y); B.u[3] = cvtpk(hi.z, hi.w);
            hb[t][kt] = B.v;
        }
    }

    const bool ok0 = (n0 + m15) < N;
    const bool ok1 = (n0 + 16 + m15) < N;
    uint16_t* prow0 = pre + (size_t)(n0 + m15) * H;
    uint16_t* prow1 = pre + (size_t)(n0 + 16 + m15) * H;

#pragma unroll
    for (int ct = 0; ct < 8; ct++) {
        f32x4 acc0 = {0.f, 0.f, 0.f, 0.f};
        f32x4 acc1 = {0.f, 0.f, 0.f, 0.f};
#pragma unroll
        for (int kt = 0; kt < 4; kt++) {
            bf16x8 afr = *(const bf16x8*)(Bfrag + ((size_t)(kt * 8 + ct) * 64 + lane) * 8);
            acc0 = __builtin_amdgcn_mfma_f32_16x16x32_bf16(afr, hb[0][kt], acc0, 0, 0, 0);
            acc1 = __builtin_amdgcn_mfma_f32_16x16x32_bf16(afr, hb[1][kt], acc1, 0, 0, 0);
        }
        float4 bv = {0.f, 0.f, 0.f, 0.f};
        if (ct < 4) bv = *(const float4*)(b1 + ct * 16 + quad * 4);   // chans < 64 get bias
        const int off = ct * 16 + quad * 4;
        if (ok0) {
            uint32_t p0 = cvtpk(acc0[0] + bv.x, acc0[1] + bv.y);
            uint32_t p1 = cvtpk(acc0[2] + bv.z, acc0[3] + bv.w);
            *(uint2*)(prow0 + off) = uint2{p0, p1};
        }
        if (ok1) {
            uint32_t p0 = cvtpk(acc1[0] + bv.x, acc1[1] + bv.y);
            uint32_t p1 = cvtpk(acc1[2] + bv.z, acc1[3] + bv.w);
            *(uint2*)(prow1 + off) = uint2{p0, p1};
        }
    }
}

// ---------------- per-edge MLP: MFMA layers 2+3, 128 edges/wave, no LDS -----
__global__ void __launch_bounds__(256, 8) edge_mlp(
    const uint16_t* __restrict__ pre,
    const int* __restrict__ src, const int* __restrict__ dst,
    const uint16_t* __restrict__ EFrag,
    const float* __restrict__ b2, const float* __restrict__ b3,
    float* __restrict__ out, long E)
{
    const int wave = threadIdx.x >> 6;
    const int lane = threadIdx.x & 63;
    const int m15  = lane & 15;
    const int quad = lane >> 4;

    // Preload B-fragments (L2-hot) and biases.
    bf16x8 bL2[4], bL3;
#pragma unroll
    for (int f = 0; f < 4; f++) bL2[f] = *(const bf16x8*)(EFrag + (f * 64 + lane) * 8);
    bL3 = *(const bf16x8*)(EFrag + (4 * 64 + lane) * 8);
    const float4 vb2a4 = *(const float4*)(b2 + quad * 4);
    const float4 vb2b4 = *(const float4*)(b2 + 16 + quad * 4);
    const float vb3  = (m15 < 6) ? b3[m15] : 0.f;

    const long e0 = (long)(blockIdx.x * 4 + wave) * 128;
    if (e0 >= E) return;

    // ---- 32 gathers issued upfront: flat regs, 32-bit byte offsets ----------
    // pre row = 256 B; per subtile st, edge = e0+st*16+m15; lane reads 2x16B
    // per side (src half [0,128), dst half [128,256)).
    const char* preb = (const char*)pre;
    uint32_t oa[8], ob[8];
#pragma unroll
    for (int st = 0; st < 8; st++) {
        long e = e0 + st * 16 + m15;
        if (e >= E) e = E - 1;                       // stores guarded below
        oa[st] = (uint32_t)src[e] * 256u + (uint32_t)quad * 16u;
        ob[st] = (uint32_t)dst[e] * 256u + 128u + (uint32_t)quad * 16u;
    }
    uint4 ga[8][2], gb[8][2];
#pragma unroll
    for (int st = 0; st < 8; st++) {
        ga[st][0] = *(const uint4*)(preb + oa[st]);
        ga[st][1] = *(const uint4*)(preb + oa[st] + 64);
        gb[st][0] = *(const uint4*)(preb + ob[st]);
        gb[st][1] = *(const uint4*)(preb + ob[st] + 64);
    }

    // bpermute byte-addresses for the layer-3 redistribution (see header map).
    const int addrA = (((quad & 1) << 5) | m15) << 2;   // lane (q&1)*2*16 + m15
    const int addrB = addrA + 64;                       // +16 lanes
    const bool hiNT = (quad >= 2);

    // ---- per subtile: layer 2 (2x2 MFMA) -> bpermute -> layer 3 (1 MFMA) ----
#pragma unroll
    for (int st = 0; st < 8; st++) {
        union { bf16x8 v; uint32_t u[4]; } A0, A1;
        A0.u[0] = bfadd2_relu(ga[st][0].x, gb[st][0].x);
        A0.u[1] = bfadd2_relu(ga[st][0].y, gb[st][0].y);
        A0.u[2] = bfadd2_relu(ga[st][0].z, gb[st][0].z);
        A0.u[3] = bfadd2_relu(ga[st][0].w, gb[st][0].w);
        A1.u[0] = bfadd2_relu(ga[st][1].x, gb[st][1].x);
        A1.u[1] = bfadd2_relu(ga[st][1].y, gb[st][1].y);
        A1.u[2] = bfadd2_relu(ga[st][1].z, gb[st][1].z);
        A1.u[3] = bfadd2_relu(ga[st][1].w, gb[st][1].w);

        uint32_t pk[2][2];                       // [nt][pair]: z chans, packed bf16
#pragma unroll
        for (int nt = 0; nt < 2; nt++) {
            f32x4 acc = {0.f, 0.f, 0.f, 0.f};
            acc = __builtin_amdgcn_mfma_f32_16x16x32_bf16(bL2[nt],     A0.v, acc, 0, 0, 0);
            acc = __builtin_amdgcn_mfma_f32_16x16x32_bf16(bL2[2 + nt], A1.v, acc, 0, 0, 0);
            const float4 bv = nt ? vb2b4 : vb2a4;
            pk[nt][0] = cvtpk(fmaxf(acc[0] + bv.x, 0.f), fmaxf(acc[1] + bv.y, 0.f));
            pk[nt][1] = cvtpk(fmaxf(acc[2] + bv.z, 0.f), fmaxf(acc[3] + bv.w, 0.f));
        }

        // Redistribute z to layer-3 A-frag layout (crossbar only, no LDS mem).
        int d0n0 = __builtin_amdgcn_ds_bpermute(addrA, (int)pk[0][0]);
        int d1n0 = __builtin_amdgcn_ds_bpermute(addrA, (int)pk[0][1]);
        int d2n0 = __builtin_amdgcn_ds_bpermute(addrB, (int)pk[0][0]);
        int d3n0 = __builtin_amdgcn_ds_bpermute(addrB, (int)pk[0][1]);
        int d0n1 = __builtin_amdgcn_ds_bpermute(addrA, (int)pk[1][0]);
        int d1n1 = __builtin_amdgcn_ds_bpermute(addrA, (int)pk[1][1]);
        int d2n1 = __builtin_amdgcn_ds_bpermute(addrB, (int)pk[1][0]);
        int d3n1 = __builtin_amdgcn_ds_bpermute(addrB, (int)pk[1][1]);
        union { bf16x8 v; int u[4]; } A3;
        A3.u[0] = hiNT ? d0n1 : d0n0;
        A3.u[1] = hiNT ? d1n1 : d1n0;
        A3.u[2] = hiNT ? d2n1 : d2n0;
        A3.u[3] = hiNT ? d3n1 : d3n0;

        f32x4 o = {0.f, 0.f, 0.f, 0.f};
        o = __builtin_amdgcn_mfma_f32_16x16x32_bf16(A3.v, bL3, o, 0, 0, 0);
        if (m15 < 6) {
#pragma unroll
            for (int r = 0; r < 4; r++) {
                long e = e0 + st * 16 + quad * 4 + r;
                if (e < E) out[e * 6 + m15] = o[r] + vb3;
            }
        }
    }
}

extern "C" void kernel_launch(void* const* d_in, const int* in_sizes, int n_in,
                              void* d_out, int out_size, void* d_ws, size_t ws_size,
                              hipStream_t stream) {
    const float* h   = (const float*)d_in[0];
    const int*   src = (const int*)d_in[1];
    const int*   dst = (const int*)d_in[2];
    const float* W1  = (const float*)d_in[3];
    const float* b1  = (const float*)d_in[4];
    const float* W2  = (const float*)d_in[5];
    const float* b2  = (const float*)d_in[6];
    const float* W3  = (const float*)d_in[7];
    const float* b3  = (const float*)d_in[8];

    const int  N = in_sizes[0] / H;     // 100000
    const long E = in_sizes[1];         // 1600000

    char* ws = (char*)d_ws;
    uint16_t* Bfrag = (uint16_t*)ws;                 // 32 KiB
    uint16_t* EFrag = (uint16_t*)(ws + 64 * 1024);   // 5 KiB
    uint16_t* pre   = (uint16_t*)(ws + 128 * 1024);  // N*128*2 = 25.6 MB (bf16)

    prep_weights<<<64, 256, 0, stream>>>(W1, W2, W3, Bfrag, EFrag);
    node_gemm<<<(N + 127) / 128, 256, 0, stream>>>(h, Bfrag, b1, pre, N);
    const int eblocks = (int)((E + 511) / 512);      // 4 waves x 128 edges per block
    edge_mlp<<<eblocks, 256, 0, stream>>>(pre, src, dst, EFrag, b2, b3,
                                          (float*)d_out, E);
}

// Round 4
// 188.217 us; speedup vs baseline: 1.6949x; 1.6949x over previous
//
#include <hip/hip_runtime.h>
#include <hip/hip_bf16.h>
#include <stdint.h>

// Per-edge MLP  out = relu(relu([h[src],h[dst]] @ W1.T + b1) @ W2.T + b2) @ W3.T + b3
// N=100000, H=128, E=1.6M, layers 256->64->32->6, fp32 in/out.
//
// R12: R9's proven structure (64 edges/wave, LDS z-slab) + forced gather ILP.
// R11 post-mortem: __launch_bounds__(256,8) capped VGPR at ~64 -> 128 VGPRs of
// gather data spilled to scratch (WRITE_SIZE 37->372MB, dur 200us). R9
// post-mortem: VGPR_Count=60 < 64 VGPRs of gather dests => compiler SANK the
// 16 upfront loads to their uses (~4 in flight, not 16); per-wave stall
// ~16000cyc = (16/4)*~1000cyc serial misses. Fix: sched_barrier(0) after the
// gather-issue block pins all 16 loads before any compute -> 16 dest regs
// forced live -> allocator must give ~130-170 VGPR (NO min-waves cap this
// time). Trades static occupancy (8->4 waves/SIMD) for 4x memory ILP;
// achieved occupancy was only ~2.7/SIMD anyway.
// node_gemm / prep_weights unchanged from R9 (passed, absmax 0.00195).
//
// MFMA 16x16x32_bf16 layouts (m89/m91-verified):
//   A[m=lane&15][k=(lane>>4)*8+j], B[k=(lane>>4)*8+j][n=lane&15],
//   C/D: col=lane&15, row=(lane>>4)*4+reg.  A- and B-frag lane maps are the
//   same pattern, so mfma(W,X) vs mfma(X,W) transposes D for free.

#define H 128

typedef short bf16x8 __attribute__((ext_vector_type(8)));
typedef float f32x4  __attribute__((ext_vector_type(4)));

__device__ __forceinline__ uint16_t f2bf(float f) {           // RNE fp32->bf16 (prep only)
    uint32_t u = __float_as_uint(f);
    return (uint16_t)((u + 0x7fffu + ((u >> 16) & 1u)) >> 16);
}

// HW RNE pack of two f32 into packed bf16 (1 VALU inst; no builtin on gfx950).
__device__ __forceinline__ uint32_t cvtpk(float lo, float hi) {
    uint32_t r;
    asm("v_cvt_pk_bf16_f32 %0, %1, %2" : "=v"(r) : "v"(lo), "v"(hi));
    return r;
}

// relu(a+b) on a packed bf16 pair: exact unpack via shifts, f32 math, HW RNE pack.
__device__ __forceinline__ uint32_t bfadd2_relu(uint32_t a, uint32_t b) {
    float alo = __uint_as_float(a << 16);
    float ahi = __uint_as_float(a & 0xffff0000u);
    float blo = __uint_as_float(b << 16);
    float bhi = __uint_as_float(b & 0xffff0000u);
    float slo = fmaxf(alo + blo, 0.f);
    float shi = fmaxf(ahi + bhi, 0.f);
    return cvtpk(slo, shi);
}

// ---------------- weight prep (unchanged) ------------------------------------
// Bfrag: concat-W1, 4 ktiles x 8 tiles (32 KB):
//   i = ((kt*8+ct)*64+lane)*8+j -> W1cat[n=ct*16+(lane&15)][k=kt*32+(lane>>4)*8+j]
// EFrag: 5 frags x 64 lanes x 8 bf16 (5 KB): W2 (4 frags) + W3 zero-padded.
__global__ void prep_weights(const float* __restrict__ W1,
                             const float* __restrict__ W2,
                             const float* __restrict__ W3,
                             uint16_t* __restrict__ Bfrag,
                             uint16_t* __restrict__ EFrag)
{
    int t = blockIdx.x * blockDim.x + threadIdx.x;
    int stride = gridDim.x * blockDim.x;
    for (int i = t; i < 4 * 8 * 64 * 8; i += stride) {
        int j    = i & 7;
        int lane = (i >> 3) & 63;
        int nt   = (i >> 9) & 7;
        int kt   = (i >> 12);
        int k = kt * 32 + (lane >> 4) * 8 + j;
        int n = nt * 16 + (lane & 15);
        float v = (n < 64) ? W1[n * 256 + k] : W1[(n - 64) * 256 + 128 + k];
        Bfrag[i] = f2bf(v);
    }
    for (int i = t; i < 5 * 64 * 8; i += stride) {
        int j    = i & 7;
        int lane = (i >> 3) & 63;
        int f    = i >> 9;
        uint16_t v;
        if (f < 4) {
            int kt = f >> 1, nt = f & 1;
            int k = kt * 32 + (lane >> 4) * 8 + j;
            int n = nt * 16 + (lane & 15);
            v = f2bf(W2[n * 64 + k]);
        } else {
            int k = (lane >> 4) * 8 + j;
            int n = lane & 15;
            v = (n < 6) ? f2bf(W3[n * 32 + k]) : (uint16_t)0;
        }
        EFrag[i] = v;
    }
}

// ---------------- per-node precompute: pre = h @ concat-W1 (+b1), MFMA ------
// Operand-swapped: D[m=chan][n=node] = mfma(A=W1frag, B=hfrag). Unchanged.
__global__ void __launch_bounds__(256) node_gemm(
    const float* __restrict__ h,
    const uint16_t* __restrict__ Bfrag,
    const float* __restrict__ b1,
    uint16_t* __restrict__ pre, int N)
{
    const int wave = threadIdx.x >> 6;
    const int lane = threadIdx.x & 63;
    const int n0 = (blockIdx.x * 4 + wave) * 32;
    if (n0 >= N) return;

    const int m15  = lane & 15;
    const int quad = lane >> 4;

    // B-fragments from h rows: B[k=kt*32+quad*8+j][node=m15] (fp32->bf16 RNE).
    bf16x8 hb[2][4];
#pragma unroll
    for (int t = 0; t < 2; t++) {
        int row = n0 + t * 16 + m15; if (row >= N) row = N - 1;   // stores guarded
        const float* hrow = h + (size_t)row * H + quad * 8;
#pragma unroll
        for (int kt = 0; kt < 4; kt++) {
            float4 lo = *(const float4*)(hrow + kt * 32);
            float4 hi = *(const float4*)(hrow + kt * 32 + 4);
            union { bf16x8 v; uint32_t u[4]; } B;
            B.u[0] = cvtpk(lo.x, lo.y); B.u[1] = cvtpk(lo.z, lo.w);
            B.u[2] = cvtpk(hi.x, hi.y); B.u[3] = cvtpk(hi.z, hi.w);
            hb[t][kt] = B.v;
        }
    }

    const bool ok0 = (n0 + m15) < N;
    const bool ok1 = (n0 + 16 + m15) < N;
    uint16_t* prow0 = pre + (size_t)(n0 + m15) * H;
    uint16_t* prow1 = pre + (size_t)(n0 + 16 + m15) * H;

#pragma unroll
    for (int ct = 0; ct < 8; ct++) {
        f32x4 acc0 = {0.f, 0.f, 0.f, 0.f};
        f32x4 acc1 = {0.f, 0.f, 0.f, 0.f};
#pragma unroll
        for (int kt = 0; kt < 4; kt++) {
            bf16x8 afr = *(const bf16x8*)(Bfrag + ((size_t)(kt * 8 + ct) * 64 + lane) * 8);
            acc0 = __builtin_amdgcn_mfma_f32_16x16x32_bf16(afr, hb[0][kt], acc0, 0, 0, 0);
            acc1 = __builtin_amdgcn_mfma_f32_16x16x32_bf16(afr, hb[1][kt], acc1, 0, 0, 0);
        }
        float4 bv = {0.f, 0.f, 0.f, 0.f};
        if (ct < 4) bv = *(const float4*)(b1 + ct * 16 + quad * 4);   // chans < 64 get bias
        const int off = ct * 16 + quad * 4;
        if (ok0) {
            uint32_t p0 = cvtpk(acc0[0] + bv.x, acc0[1] + bv.y);
            uint32_t p1 = cvtpk(acc0[2] + bv.z, acc0[3] + bv.w);
            *(uint2*)(prow0 + off) = uint2{p0, p1};
        }
        if (ok1) {
            uint32_t p0 = cvtpk(acc1[0] + bv.x, acc1[1] + bv.y);
            uint32_t p1 = cvtpk(acc1[2] + bv.z, acc1[3] + bv.w);
            *(uint2*)(prow1 + off) = uint2{p0, p1};
        }
    }
}

// ---------------- per-edge MLP: MFMA layers 2+3, 64 edges/wave ---------------
// NO min-waves launch bound (R11 lesson): let the allocator keep all 16 gather
// dests live. sched_barrier(0) pins the issue order.
__global__ void __launch_bounds__(256) edge_mlp(
    const uint16_t* __restrict__ pre,
    const int* __restrict__ src, const int* __restrict__ dst,
    const uint16_t* __restrict__ EFrag,
    const float* __restrict__ b2, const float* __restrict__ b3,
    float* __restrict__ out, long E)
{
    __shared__ uint16_t zbuf[4][64 * 40];   // wave-private z slab, stride 40 halves

    const int wave = threadIdx.x >> 6;
    const int lane = threadIdx.x & 63;
    const int m15  = lane & 15;
    const int quad = lane >> 4;
    uint16_t* zw = &zbuf[wave][0];

    const long e0 = (long)(blockIdx.x * 4 + wave) * 64;
    if (e0 >= E) return;

    // ---- 1) issue index loads (longest dependency chain) --------------------
    long ea = e0 + m15;           // subtile st uses edge e0+st*16+m15
    long eb = (ea + 16 < E) ? ea + 16 : E - 1;
    long ec = (ea + 32 < E) ? ea + 32 : E - 1;
    long ed = (ea + 48 < E) ? ea + 48 : E - 1;
    if (ea >= E) ea = E - 1;
    int sa = src[ea], da = dst[ea];
    int sb = src[eb], db = dst[eb];
    int sc = src[ec], dc = dst[ec];
    int sd = src[ed], dd = dst[ed];

    // ---- 2) preload B-fragments (L2-hot) and biases meanwhile ---------------
    bf16x8 bL2[4], bL3;
#pragma unroll
    for (int f = 0; f < 4; f++) bL2[f] = *(const bf16x8*)(EFrag + (f * 64 + lane) * 8);
    bL3 = *(const bf16x8*)(EFrag + (4 * 64 + lane) * 8);
    const float4 vb2a4 = *(const float4*)(b2 + quad * 4);
    const float4 vb2b4 = *(const float4*)(b2 + 16 + quad * 4);
    const float vb3  = (m15 < 6) ? b3[m15] : 0.f;

    // ---- 3) issue ALL 16 gathers: flat regs, 32-bit byte offsets ------------
    // pre row = 256 B; lane reads 2x16B per side (src half [0,128), dst [128,256)).
    const char* preb = (const char*)pre;
    const uint32_t qo = (uint32_t)quad * 16u;
    uint32_t oa0 = (uint32_t)sa * 256u + qo,        ob0 = (uint32_t)da * 256u + 128u + qo;
    uint32_t oa1 = (uint32_t)sb * 256u + qo,        ob1 = (uint32_t)db * 256u + 128u + qo;
    uint32_t oa2 = (uint32_t)sc * 256u + qo,        ob2 = (uint32_t)dc * 256u + 128u + qo;
    uint32_t oa3 = (uint32_t)sd * 256u + qo,        ob3 = (uint32_t)dd * 256u + 128u + qo;

    uint4 a00 = *(const uint4*)(preb + oa0);
    uint4 a01 = *(const uint4*)(preb + oa0 + 64);
    uint4 b00 = *(const uint4*)(preb + ob0);
    uint4 b01 = *(const uint4*)(preb + ob0 + 64);
    uint4 a10 = *(const uint4*)(preb + oa1);
    uint4 a11 = *(const uint4*)(preb + oa1 + 64);
    uint4 b10 = *(const uint4*)(preb + ob1);
    uint4 b11 = *(const uint4*)(preb + ob1 + 64);
    uint4 a20 = *(const uint4*)(preb + oa2);
    uint4 a21 = *(const uint4*)(preb + oa2 + 64);
    uint4 b20 = *(const uint4*)(preb + ob2);
    uint4 b21 = *(const uint4*)(preb + ob2 + 64);
    uint4 a30 = *(const uint4*)(preb + oa3);
    uint4 a31 = *(const uint4*)(preb + oa3 + 64);
    uint4 b30 = *(const uint4*)(preb + ob3);
    uint4 b31 = *(const uint4*)(preb + ob3 + 64);

    // Pin: every load above must be ISSUED before anything below is scheduled.
    // Forces all 16 uint4 dests simultaneously live -> real vmcnt pipelining.
    __builtin_amdgcn_sched_barrier(0);

    // ---- layer 2 per subtile: packed-bf16 relu(a+b) -> frag -> 2x2 MFMA -----
    // Operand-swapped mfma(W2frag, X) => lane holds z[edge=m15][n=nt*16+quad*4+r]
    // (4 consecutive n) -> 2x cvt_pk + one ds_write_b64 into z-slab laid out
    // [edge][n] stride 40 halves -- exactly what layer 3's ds_read_b128 expects.
#define DO_SUBTILE(ST, UA0, UB0, UA1, UB1)                                        \
    {                                                                             \
        union { bf16x8 v; uint32_t u[4]; } A0, A1;                                \
        A0.u[0] = bfadd2_relu(UA0.x, UB0.x);                                      \
        A0.u[1] = bfadd2_relu(UA0.y, UB0.y);                                      \
        A0.u[2] = bfadd2_relu(UA0.z, UB0.z);                                      \
        A0.u[3] = bfadd2_relu(UA0.w, UB0.w);                                      \
        A1.u[0] = bfadd2_relu(UA1.x, UB1.x);                                      \
        A1.u[1] = bfadd2_relu(UA1.y, UB1.y);                                      \
        A1.u[2] = bfadd2_relu(UA1.z, UB1.z);                                      \
        A1.u[3] = bfadd2_relu(UA1.w, UB1.w);                                      \
        _Pragma("unroll")                                                         \
        for (int nt = 0; nt < 2; nt++) {                                          \
            f32x4 acc = {0.f, 0.f, 0.f, 0.f};                                     \
            acc = __builtin_amdgcn_mfma_f32_16x16x32_bf16(bL2[nt], A0.v, acc, 0, 0, 0); \
            acc = __builtin_amdgcn_mfma_f32_16x16x32_bf16(bL2[2 + nt], A1.v, acc, 0, 0, 0); \
            const float4 bv = nt ? vb2b4 : vb2a4;                                 \
            uint32_t p0 = cvtpk(fmaxf(acc[0] + bv.x, 0.f), fmaxf(acc[1] + bv.y, 0.f)); \
            uint32_t p1 = cvtpk(fmaxf(acc[2] + bv.z, 0.f), fmaxf(acc[3] + bv.w, 0.f)); \
            *(uint2*)(zw + ((ST) * 16 + m15) * 40 + nt * 16 + quad * 4) = uint2{p0, p1}; \
        }                                                                         \
    }

    DO_SUBTILE(0, a00, b00, a01, b01)
    DO_SUBTILE(1, a10, b10, a11, b11)
    DO_SUBTILE(2, a20, b20, a21, b21)
    DO_SUBTILE(3, a30, b30, a31, b31)
#undef DO_SUBTILE

    // ---- layer 3: LDS A-frags -> 1 MFMA per subtile -------------------------
#pragma unroll
    for (int st = 0; st < 4; st++) {
        bf16x8 a3 = *(const bf16x8*)(zw + (st * 16 + m15) * 40 + quad * 8);
        f32x4 o = {0.f, 0.f, 0.f, 0.f};
        o = __builtin_amdgcn_mfma_f32_16x16x32_bf16(a3, bL3, o, 0, 0, 0);
        if (m15 < 6) {
#pragma unroll
            for (int r = 0; r < 4; r++) {
                long e = e0 + st * 16 + quad * 4 + r;
                if (e < E) out[e * 6 + m15] = o[r] + vb3;
            }
        }
    }
}

extern "C" void kernel_launch(void* const* d_in, const int* in_sizes, int n_in,
                              void* d_out, int out_size, void* d_ws, size_t ws_size,
                              hipStream_t stream) {
    const float* h   = (const float*)d_in[0];
    const int*   src = (const int*)d_in[1];
    const int*   dst = (const int*)d_in[2];
    const float* W1  = (const float*)d_in[3];
    const float* b1  = (const float*)d_in[4];
    const float* W2  = (const float*)d_in[5];
    const float* b2  = (const float*)d_in[6];
    const float* W3  = (const float*)d_in[7];
    const float* b3  = (const float*)d_in[8];

    const int  N = in_sizes[0] / H;     // 100000
    const long E = in_sizes[1];         // 1600000

    char* ws = (char*)d_ws;
    uint16_t* Bfrag = (uint16_t*)ws;                 // 32 KiB
    uint16_t* EFrag = (uint16_t*)(ws + 64 * 1024);   // 5 KiB
    uint16_t* pre   = (uint16_t*)(ws + 128 * 1024);  // N*128*2 = 25.6 MB (bf16)

    prep_weights<<<64, 256, 0, stream>>>(W1, W2, W3, Bfrag, EFrag);
    node_gemm<<<(N + 127) / 128, 256, 0, stream>>>(h, Bfrag, b1, pre, N);
    const int eblocks = (int)((E + 255) / 256);      // 4 waves x 64 edges per block
    edge_mlp<<<eblocks, 256, 0, stream>>>(pre, src, dst, EFrag, b2, b3,
                                          (float*)d_out, E);
}

// Round 5
// 183.967 us; speedup vs baseline: 1.7340x; 1.0231x over previous
//
#include <hip/hip_runtime.h>
#include <hip/hip_bf16.h>
#include <stdint.h>

// Per-edge MLP  out = relu(relu([h[src],h[dst]] @ W1.T + b1) @ W2.T + b2) @ W3.T + b3
// N=100000, H=128, E=1.6M, layers 256->64->32->6, fp32 in/out.
//
// R13: edge_mlp gather path rebuilt. R12 post-mortem: sched_barrier couldn't
// stop the compiler sinking the 16 C++ gathers (VGPR stayed 64, dur identical
// to R9/R8 at ~68us; no measured pipe >41%). Two invisible-candidate limiters:
// (a) loads serialized (1-2 in flight) -> vmcnt latency bound;
// (b) divergent-gather line-transaction rate: old lane order put 16 DIFFERENT
//     rows in each 16-lane quarter-wave -> up to 64 line-txns/inst vs 16 min.
// Fixes, both compiler-proof:
//  - inline-asm global_load_dwordx4 + hand-counted s_waitcnt vmcnt(8/8/4/0)
//    (depth-2 subtile pipeline, 8-12 loads guaranteed in flight). All C++
//    loads laundered/consumed before the asm region so compiler waitcnt
//    insertion can't inject vmcnt(0) into the loop. sched_barrier(0) after
//    every waitcnt (rule #18: reg-only consumers hoist past asm waits).
//  - gather lane-reorder: edge=lane>>2, chunk=lane&3 -> 4 adjacent lanes read
//    one contiguous 64B line (16 lines/inst guaranteed). relu(a+b) pairs up
//    in gather order (lane holds matching src/dst chunks); repack to A-frag
//    layout is a pure lane permutation: target lane q*16+m pulls its 8-dword
//    payload from lane 4m+q via 8 ds_bpermute/subtile.
// node_gemm / prep_weights unchanged (proven, absmax 0.00195).
//
// MFMA 16x16x32_bf16 layouts (m89/m91-verified):
//   A[m=lane&15][k=(lane>>4)*8+j], B[k=(lane>>4)*8+j][n=lane&15],
//   C/D: col=lane&15, row=(lane>>4)*4+reg.

#define H 128

typedef short bf16x8 __attribute__((ext_vector_type(8)));
typedef float f32x4  __attribute__((ext_vector_type(4)));
typedef uint32_t u32x4 __attribute__((ext_vector_type(4)));

__device__ __forceinline__ uint16_t f2bf(float f) {           // RNE fp32->bf16 (prep only)
    uint32_t u = __float_as_uint(f);
    return (uint16_t)((u + 0x7fffu + ((u >> 16) & 1u)) >> 16);
}

// HW RNE pack of two f32 into packed bf16 (1 VALU inst; no builtin on gfx950).
__device__ __forceinline__ uint32_t cvtpk(float lo, float hi) {
    uint32_t r;
    asm("v_cvt_pk_bf16_f32 %0, %1, %2" : "=v"(r) : "v"(lo), "v"(hi));
    return r;
}

// relu(a+b) on a packed bf16 pair: exact unpack via shifts, f32 math, HW RNE pack.
__device__ __forceinline__ uint32_t bfadd2_relu(uint32_t a, uint32_t b) {
    float alo = __uint_as_float(a << 16);
    float ahi = __uint_as_float(a & 0xffff0000u);
    float blo = __uint_as_float(b << 16);
    float bhi = __uint_as_float(b & 0xffff0000u);
    float slo = fmaxf(alo + blo, 0.f);
    float shi = fmaxf(ahi + bhi, 0.f);
    return cvtpk(slo, shi);
}

// ---------------- weight prep (unchanged) ------------------------------------
__global__ void prep_weights(const float* __restrict__ W1,
                             const float* __restrict__ W2,
                             const float* __restrict__ W3,
                             uint16_t* __restrict__ Bfrag,
                             uint16_t* __restrict__ EFrag)
{
    int t = blockIdx.x * blockDim.x + threadIdx.x;
    int stride = gridDim.x * blockDim.x;
    for (int i = t; i < 4 * 8 * 64 * 8; i += stride) {
        int j    = i & 7;
        int lane = (i >> 3) & 63;
        int nt   = (i >> 9) & 7;
        int kt   = (i >> 12);
        int k = kt * 32 + (lane >> 4) * 8 + j;
        int n = nt * 16 + (lane & 15);
        float v = (n < 64) ? W1[n * 256 + k] : W1[(n - 64) * 256 + 128 + k];
        Bfrag[i] = f2bf(v);
    }
    for (int i = t; i < 5 * 64 * 8; i += stride) {
        int j    = i & 7;
        int lane = (i >> 3) & 63;
        int f    = i >> 9;
        uint16_t v;
        if (f < 4) {
            int kt = f >> 1, nt = f & 1;
            int k = kt * 32 + (lane >> 4) * 8 + j;
            int n = nt * 16 + (lane & 15);
            v = f2bf(W2[n * 64 + k]);
        } else {
            int k = (lane >> 4) * 8 + j;
            int n = lane & 15;
            v = (n < 6) ? f2bf(W3[n * 32 + k]) : (uint16_t)0;
        }
        EFrag[i] = v;
    }
}

// ---------------- per-node precompute: pre = h @ concat-W1 (+b1), MFMA ------
// Operand-swapped: D[m=chan][n=node] = mfma(A=W1frag, B=hfrag). Unchanged.
__global__ void __launch_bounds__(256) node_gemm(
    const float* __restrict__ h,
    const uint16_t* __restrict__ Bfrag,
    const float* __restrict__ b1,
    uint16_t* __restrict__ pre, int N)
{
    const int wave = threadIdx.x >> 6;
    const int lane = threadIdx.x & 63;
    const int n0 = (blockIdx.x * 4 + wave) * 32;
    if (n0 >= N) return;

    const int m15  = lane & 15;
    const int quad = lane >> 4;

    bf16x8 hb[2][4];
#pragma unroll
    for (int t = 0; t < 2; t++) {
        int row = n0 + t * 16 + m15; if (row >= N) row = N - 1;   // stores guarded
        const float* hrow = h + (size_t)row * H + quad * 8;
#pragma unroll
        for (int kt = 0; kt < 4; kt++) {
            float4 lo = *(const float4*)(hrow + kt * 32);
            float4 hi = *(const float4*)(hrow + kt * 32 + 4);
            union { bf16x8 v; uint32_t u[4]; } B;
            B.u[0] = cvtpk(lo.x, lo.y); B.u[1] = cvtpk(lo.z, lo.w);
            B.u[2] = cvtpk(hi.x, hi.y); B.u[3] = cvtpk(hi.z, hi.w);
            hb[t][kt] = B.v;
        }
    }

    const bool ok0 = (n0 + m15) < N;
    const bool ok1 = (n0 + 16 + m15) < N;
    uint16_t* prow0 = pre + (size_t)(n0 + m15) * H;
    uint16_t* prow1 = pre + (size_t)(n0 + 16 + m15) * H;

#pragma unroll
    for (int ct = 0; ct < 8; ct++) {
        f32x4 acc0 = {0.f, 0.f, 0.f, 0.f};
        f32x4 acc1 = {0.f, 0.f, 0.f, 0.f};
#pragma unroll
        for (int kt = 0; kt < 4; kt++) {
            bf16x8 afr = *(const bf16x8*)(Bfrag + ((size_t)(kt * 8 + ct) * 64 + lane) * 8);
            acc0 = __builtin_amdgcn_mfma_f32_16x16x32_bf16(afr, hb[0][kt], acc0, 0, 0, 0);
            acc1 = __builtin_amdgcn_mfma_f32_16x16x32_bf16(afr, hb[1][kt], acc1, 0, 0, 0);
        }
        float4 bv = {0.f, 0.f, 0.f, 0.f};
        if (ct < 4) bv = *(const float4*)(b1 + ct * 16 + quad * 4);
        const int off = ct * 16 + quad * 4;
        if (ok0) {
            uint32_t p0 = cvtpk(acc0[0] + bv.x, acc0[1] + bv.y);
            uint32_t p1 = cvtpk(acc0[2] + bv.z, acc0[3] + bv.w);
            *(uint2*)(prow0 + off) = uint2{p0, p1};
        }
        if (ok1) {
            uint32_t p0 = cvtpk(acc1[0] + bv.x, acc1[1] + bv.y);
            uint32_t p1 = cvtpk(acc1[2] + bv.z, acc1[3] + bv.w);
            *(uint2*)(prow1 + off) = uint2{p0, p1};
        }
    }
}

// ---- asm gather: 16B load, base SGPR pair + 32-bit voffset (+imm 64) --------
#define GLOAD(dst, off)   asm volatile("global_load_dwordx4 %0, %1, %2"           \
                                       : "=v"(dst) : "v"(off), "s"(preb))
#define GLOAD64(dst, off) asm volatile("global_load_dwordx4 %0, %1, %2 offset:64" \
                                       : "=v"(dst) : "v"(off), "s"(preb))
// counted wait + fence (rule #18: reg-only consumers hoist past asm waits)
#define VMWAIT(N) do { asm volatile("s_waitcnt vmcnt(" #N ")" ::: "memory");      \
                       __builtin_amdgcn_sched_barrier(0); } while (0)
#define LAUNDER(x) asm volatile("" : "+v"(x))

// ---------------- per-edge MLP: MFMA layers 2+3, 64 edges/wave ---------------
__global__ void __launch_bounds__(256) edge_mlp(
    const uint16_t* __restrict__ pre,
    const int* __restrict__ src, const int* __restrict__ dst,
    const uint16_t* __restrict__ EFrag,
    const float* __restrict__ b2, const float* __restrict__ b3,
    float* __restrict__ out, long E)
{
    __shared__ uint16_t zbuf[4][64 * 40];   // wave-private z slab, stride 40 halves

    const int wave = threadIdx.x >> 6;
    const int lane = threadIdx.x & 63;
    const int m15  = lane & 15;      // compute-side: edge-in-subtile
    const int quad = lane >> 4;      // compute-side: k-chunk group
    const int em   = lane >> 2;      // gather-side: edge-in-subtile (0..15)
    const int ch4  = lane & 3;       // gather-side: 16B chunk in 64B line
    uint16_t* zw = &zbuf[wave][0];

    const long e0 = (long)(blockIdx.x * 4 + wave) * 64;
    if (e0 >= E) return;

    // ---- C++-visible loads: indices -> offsets, weight frags, biases --------
    uint32_t oa[4], ob[4];
#pragma unroll
    for (int st = 0; st < 4; st++) {
        long e = e0 + st * 16 + em;
        if (e >= E) e = E - 1;                       // stores guarded below
        oa[st] = (uint32_t)src[e] * 256u + (uint32_t)ch4 * 16u;
        ob[st] = (uint32_t)dst[e] * 256u + 128u + (uint32_t)ch4 * 16u;
    }
    bf16x8 bL2[4], bL3;
#pragma unroll
    for (int f = 0; f < 4; f++) bL2[f] = *(const bf16x8*)(EFrag + (f * 64 + lane) * 8);
    bL3 = *(const bf16x8*)(EFrag + (4 * 64 + lane) * 8);
    float4 t2a = *(const float4*)(b2 + quad * 4);
    float4 t2b = *(const float4*)(b2 + 16 + quad * 4);
    float ba0 = t2a.x, ba1 = t2a.y, ba2 = t2a.z, ba3 = t2a.w;
    float bb0 = t2b.x, bb1 = t2b.y, bb2 = t2b.z, bb3 = t2b.w;
    float vb3 = (m15 < 6) ? b3[m15] : 0.f;

    // Launder load results: breaks load->use provenance so the compiler's
    // waitcnt pass settles all C++ loads HERE, not inside the asm pipeline.
    LAUNDER(bL2[0]); LAUNDER(bL2[1]); LAUNDER(bL2[2]); LAUNDER(bL2[3]); LAUNDER(bL3);
    LAUNDER(ba0); LAUNDER(ba1); LAUNDER(ba2); LAUNDER(ba3);
    LAUNDER(bb0); LAUNDER(bb1); LAUNDER(bb2); LAUNDER(bb3); LAUNDER(vb3);
    asm volatile("s_waitcnt vmcnt(0)" ::: "memory");   // clean vmcnt baseline
    __builtin_amdgcn_sched_barrier(0);

    const char* preb = (const char*)pre;
    // bpermute source-lane byte addr: target (q,m) pulls from lane 4m+q.
    const int bp = ((m15 << 2) | quad) << 2;

    u32x4 s0g0, s0g1, s0g2, s0g3, s1g0, s1g1, s1g2, s1g3;
    u32x4 s2g0, s2g1, s2g2, s2g3, s3g0, s3g1, s3g2, s3g3;

#define ISSUE(ST)                                                                 \
    GLOAD  (s##ST##g0, oa[ST]);   /* src chans  8*ch4.., line 0 */                \
    GLOAD64(s##ST##g1, oa[ST]);   /* src chans 32+8*ch4, line 1 */                \
    GLOAD  (s##ST##g2, ob[ST]);   /* dst chans 64+8*ch4, line 0 */                \
    GLOAD64(s##ST##g3, ob[ST]);   /* dst chans 96+8*ch4, line 1 */

    // ---- layer 2 per subtile: relu2 in gather order -> bpermute repack ------
    // Lane s=4m+q holds y chunks {q, q+4} of edge m == exactly what A-frag
    // lane t=16q+m needs (A0 = chans 8q.., A1 = chans 32+8q..).
#define COMPUTE(ST)                                                               \
    {                                                                             \
        u32x4 Y0, Y1;                                                             \
        Y0.x = bfadd2_relu(s##ST##g0.x, s##ST##g2.x);                             \
        Y0.y = bfadd2_relu(s##ST##g0.y, s##ST##g2.y);                             \
        Y0.z = bfadd2_relu(s##ST##g0.z, s##ST##g2.z);                             \
        Y0.w = bfadd2_relu(s##ST##g0.w, s##ST##g2.w);                             \
        Y1.x = bfadd2_relu(s##ST##g1.x, s##ST##g3.x);                             \
        Y1.y = bfadd2_relu(s##ST##g1.y, s##ST##g3.y);                             \
        Y1.z = bfadd2_relu(s##ST##g1.z, s##ST##g3.z);                             \
        Y1.w = bfadd2_relu(s##ST##g1.w, s##ST##g3.w);                             \
        union { bf16x8 v; int u[4]; } A0, A1;                                     \
        A0.u[0] = __builtin_amdgcn_ds_bpermute(bp, (int)Y0.x);                    \
        A0.u[1] = __builtin_amdgcn_ds_bpermute(bp, (int)Y0.y);                    \
        A0.u[2] = __builtin_amdgcn_ds_bpermute(bp, (int)Y0.z);                    \
        A0.u[3] = __builtin_amdgcn_ds_bpermute(bp, (int)Y0.w);                    \
        A1.u[0] = __builtin_amdgcn_ds_bpermute(bp, (int)Y1.x);                    \
        A1.u[1] = __builtin_amdgcn_ds_bpermute(bp, (int)Y1.y);                    \
        A1.u[2] = __builtin_amdgcn_ds_bpermute(bp, (int)Y1.z);                    \
        A1.u[3] = __builtin_amdgcn_ds_bpermute(bp, (int)Y1.w);                    \
        _Pragma("unroll")                                                         \
        for (int nt = 0; nt < 2; nt++) {                                          \
            f32x4 acc = {0.f, 0.f, 0.f, 0.f};                                     \
            acc = __builtin_amdgcn_mfma_f32_16x16x32_bf16(bL2[nt], A0.v, acc, 0, 0, 0); \
            acc = __builtin_amdgcn_mfma_f32_16x16x32_bf16(bL2[2 + nt], A1.v, acc, 0, 0, 0); \
            const float c0 = nt ? bb0 : ba0, c1 = nt ? bb1 : ba1;                 \
            const float c2 = nt ? bb2 : ba2, c3 = nt ? bb3 : ba3;                 \
            uint32_t p0 = cvtpk(fmaxf(acc[0] + c0, 0.f), fmaxf(acc[1] + c1, 0.f)); \
            uint32_t p1 = cvtpk(fmaxf(acc[2] + c2, 0.f), fmaxf(acc[3] + c3, 0.f)); \
            *(uint2*)(zw + ((ST) * 16 + m15) * 40 + nt * 16 + quad * 4) = uint2{p0, p1}; \
        }                                                                         \
    }

    // ---- depth-2 pipeline, hand-counted vmcnt -------------------------------
    ISSUE(0) ISSUE(1)            // 8 outstanding
    ISSUE(2)                     // 12 outstanding
    VMWAIT(8);  COMPUTE(0)       // subtile-0 loads retired
    ISSUE(3)                     // <=12 outstanding
    VMWAIT(8);  COMPUTE(1)       // subtile-1 retired
    VMWAIT(4);  COMPUTE(2)       // subtile-2 retired
    VMWAIT(0);  COMPUTE(3)
#undef ISSUE
#undef COMPUTE

    // ---- layer 3: LDS A-frags -> 1 MFMA per subtile (unchanged) -------------
#pragma unroll
    for (int st = 0; st < 4; st++) {
        bf16x8 a3 = *(const bf16x8*)(zw + (st * 16 + m15) * 40 + quad * 8);
        f32x4 o = {0.f, 0.f, 0.f, 0.f};
        o = __builtin_amdgcn_mfma_f32_16x16x32_bf16(a3, bL3, o, 0, 0, 0);
        if (m15 < 6) {
#pragma unroll
            for (int r = 0; r < 4; r++) {
                long e = e0 + st * 16 + quad * 4 + r;
                if (e < E) out[e * 6 + m15] = o[r] + vb3;
            }
        }
    }
}

extern "C" void kernel_launch(void* const* d_in, const int* in_sizes, int n_in,
                              void* d_out, int out_size, void* d_ws, size_t ws_size,
                              hipStream_t stream) {
    const float* h   = (const float*)d_in[0];
    const int*   src = (const int*)d_in[1];
    const int*   dst = (const int*)d_in[2];
    const float* W1  = (const float*)d_in[3];
    const float* b1  = (const float*)d_in[4];
    const float* W2  = (const float*)d_in[5];
    const float* b2  = (const float*)d_in[6];
    const float* W3  = (const float*)d_in[7];
    const float* b3  = (const float*)d_in[8];

    const int  N = in_sizes[0] / H;     // 100000
    const long E = in_sizes[1];         // 1600000

    char* ws = (char*)d_ws;
    uint16_t* Bfrag = (uint16_t*)ws;                 // 32 KiB
    uint16_t* EFrag = (uint16_t*)(ws + 64 * 1024);   // 5 KiB
    uint16_t* pre   = (uint16_t*)(ws + 128 * 1024);  // N*128*2 = 25.6 MB (bf16)

    prep_weights<<<64, 256, 0, stream>>>(W1, W2, W3, Bfrag, EFrag);
    node_gemm<<<(N + 127) / 128, 256, 0, stream>>>(h, Bfrag, b1, pre, N);
    const int eblocks = (int)((E + 255) / 256);      // 4 waves x 64 edges per block
    edge_mlp<<<eblocks, 256, 0, stream>>>(pre, src, dst, EFrag, b2, b3,
                                          (float*)d_out, E);
}

// Round 6
// 182.279 us; speedup vs baseline: 1.7501x; 1.0093x over previous
//
#include <hip/hip_runtime.h>
#include <hip/hip_bf16.h>
#include <stdint.h>

// Per-edge MLP  out = relu(relu([h[src],h[dst]] @ W1.T + b1) @ W2.T + b2) @ W3.T + b3
// N=100000, H=128, E=1.6M, layers 256->64->32->6, fp32 in/out.
//
// R14: R13's asm-gather pipeline + ZERO-LDS edge_mlp.
// R13 post-mortem: 60.2us, occupancy 41% (13 waves/CU) despite LDS allowing
// 8 blocks/CU; Little's law: 13 waves x 12 inflight lines @ ~900cyc latency
// == measured 0.174 lines/cyc/CU => latency-bound, residency-capped.
// R11's no-LDS bpermute variant hit 70% occupancy => z-slab implicated.
// Change: replace z-slab round-trip with R11's correctness-verified
// ds_bpermute layer-3 redistribution (R13's operand-swapped layer-2 emits
// exactly R11's pk[nt] register layout). LDS_Block_Size -> 0, bank-conflict
// cycles (2.8M) gone, residency capped only by VGPR (~8 waves/SIMD).
// node_gemm / prep_weights unchanged (proven, absmax 0.00195).
//
// MFMA 16x16x32_bf16 layouts (m89/m91-verified):
//   A[m=lane&15][k=(lane>>4)*8+j], B[k=(lane>>4)*8+j][n=lane&15],
//   C/D: col=lane&15, row=(lane>>4)*4+reg.
// Layer-3 redistribution map (R11-verified):
//   source lane (quad',m15) holds z[edge=m15][chan=nt*16+quad'*4+r] as packed
//   pairs pk[nt][0]=chans{+0,+1}, pk[nt][1]=chans{+2,+3}.
//   target lane (q,m15) needs A3 = chans q*8..q*8+7 of edge m15:
//     dwords 0,1 <- lane ((q&1)*2)*16+m15   pk[q>>1][0..1]
//     dwords 2,3 <- lane ((q&1)*2+1)*16+m15 pk[q>>1][0..1]

#define H 128

typedef short bf16x8 __attribute__((ext_vector_type(8)));
typedef float f32x4  __attribute__((ext_vector_type(4)));
typedef uint32_t u32x4 __attribute__((ext_vector_type(4)));

__device__ __forceinline__ uint16_t f2bf(float f) {           // RNE fp32->bf16 (prep only)
    uint32_t u = __float_as_uint(f);
    return (uint16_t)((u + 0x7fffu + ((u >> 16) & 1u)) >> 16);
}

// HW RNE pack of two f32 into packed bf16 (1 VALU inst; no builtin on gfx950).
__device__ __forceinline__ uint32_t cvtpk(float lo, float hi) {
    uint32_t r;
    asm("v_cvt_pk_bf16_f32 %0, %1, %2" : "=v"(r) : "v"(lo), "v"(hi));
    return r;
}

// relu(a+b) on a packed bf16 pair: exact unpack via shifts, f32 math, HW RNE pack.
__device__ __forceinline__ uint32_t bfadd2_relu(uint32_t a, uint32_t b) {
    float alo = __uint_as_float(a << 16);
    float ahi = __uint_as_float(a & 0xffff0000u);
    float blo = __uint_as_float(b << 16);
    float bhi = __uint_as_float(b & 0xffff0000u);
    float slo = fmaxf(alo + blo, 0.f);
    float shi = fmaxf(ahi + bhi, 0.f);
    return cvtpk(slo, shi);
}

// ---------------- weight prep (unchanged) ------------------------------------
__global__ void prep_weights(const float* __restrict__ W1,
                             const float* __restrict__ W2,
                             const float* __restrict__ W3,
                             uint16_t* __restrict__ Bfrag,
                             uint16_t* __restrict__ EFrag)
{
    int t = blockIdx.x * blockDim.x + threadIdx.x;
    int stride = gridDim.x * blockDim.x;
    for (int i = t; i < 4 * 8 * 64 * 8; i += stride) {
        int j    = i & 7;
        int lane = (i >> 3) & 63;
        int nt   = (i >> 9) & 7;
        int kt   = (i >> 12);
        int k = kt * 32 + (lane >> 4) * 8 + j;
        int n = nt * 16 + (lane & 15);
        float v = (n < 64) ? W1[n * 256 + k] : W1[(n - 64) * 256 + 128 + k];
        Bfrag[i] = f2bf(v);
    }
    for (int i = t; i < 5 * 64 * 8; i += stride) {
        int j    = i & 7;
        int lane = (i >> 3) & 63;
        int f    = i >> 9;
        uint16_t v;
        if (f < 4) {
            int kt = f >> 1, nt = f & 1;
            int k = kt * 32 + (lane >> 4) * 8 + j;
            int n = nt * 16 + (lane & 15);
            v = f2bf(W2[n * 64 + k]);
        } else {
            int k = (lane >> 4) * 8 + j;
            int n = lane & 15;
            v = (n < 6) ? f2bf(W3[n * 32 + k]) : (uint16_t)0;
        }
        EFrag[i] = v;
    }
}

// ---------------- per-node precompute: pre = h @ concat-W1 (+b1), MFMA ------
// Operand-swapped: D[m=chan][n=node] = mfma(A=W1frag, B=hfrag). Unchanged.
__global__ void __launch_bounds__(256) node_gemm(
    const float* __restrict__ h,
    const uint16_t* __restrict__ Bfrag,
    const float* __restrict__ b1,
    uint16_t* __restrict__ pre, int N)
{
    const int wave = threadIdx.x >> 6;
    const int lane = threadIdx.x & 63;
    const int n0 = (blockIdx.x * 4 + wave) * 32;
    if (n0 >= N) return;

    const int m15  = lane & 15;
    const int quad = lane >> 4;

    bf16x8 hb[2][4];
#pragma unroll
    for (int t = 0; t < 2; t++) {
        int row = n0 + t * 16 + m15; if (row >= N) row = N - 1;   // stores guarded
        const float* hrow = h + (size_t)row * H + quad * 8;
#pragma unroll
        for (int kt = 0; kt < 4; kt++) {
            float4 lo = *(const float4*)(hrow + kt * 32);
            float4 hi = *(const float4*)(hrow + kt * 32 + 4);
            union { bf16x8 v; uint32_t u[4]; } B;
            B.u[0] = cvtpk(lo.x, lo.y); B.u[1] = cvtpk(lo.z, lo.w);
            B.u[2] = cvtpk(hi.x, hi.y); B.u[3] = cvtpk(hi.z, hi.w);
            hb[t][kt] = B.v;
        }
    }

    const bool ok0 = (n0 + m15) < N;
    const bool ok1 = (n0 + 16 + m15) < N;
    uint16_t* prow0 = pre + (size_t)(n0 + m15) * H;
    uint16_t* prow1 = pre + (size_t)(n0 + 16 + m15) * H;

#pragma unroll
    for (int ct = 0; ct < 8; ct++) {
        f32x4 acc0 = {0.f, 0.f, 0.f, 0.f};
        f32x4 acc1 = {0.f, 0.f, 0.f, 0.f};
#pragma unroll
        for (int kt = 0; kt < 4; kt++) {
            bf16x8 afr = *(const bf16x8*)(Bfrag + ((size_t)(kt * 8 + ct) * 64 + lane) * 8);
            acc0 = __builtin_amdgcn_mfma_f32_16x16x32_bf16(afr, hb[0][kt], acc0, 0, 0, 0);
            acc1 = __builtin_amdgcn_mfma_f32_16x16x32_bf16(afr, hb[1][kt], acc1, 0, 0, 0);
        }
        float4 bv = {0.f, 0.f, 0.f, 0.f};
        if (ct < 4) bv = *(const float4*)(b1 + ct * 16 + quad * 4);
        const int off = ct * 16 + quad * 4;
        if (ok0) {
            uint32_t p0 = cvtpk(acc0[0] + bv.x, acc0[1] + bv.y);
            uint32_t p1 = cvtpk(acc0[2] + bv.z, acc0[3] + bv.w);
            *(uint2*)(prow0 + off) = uint2{p0, p1};
        }
        if (ok1) {
            uint32_t p0 = cvtpk(acc1[0] + bv.x, acc1[1] + bv.y);
            uint32_t p1 = cvtpk(acc1[2] + bv.z, acc1[3] + bv.w);
            *(uint2*)(prow1 + off) = uint2{p0, p1};
        }
    }
}

// ---- asm gather: 16B load, base SGPR pair + 32-bit voffset (+imm 64) --------
#define GLOAD(dst, off)   asm volatile("global_load_dwordx4 %0, %1, %2"           \
                                       : "=v"(dst) : "v"(off), "s"(preb))
#define GLOAD64(dst, off) asm volatile("global_load_dwordx4 %0, %1, %2 offset:64" \
                                       : "=v"(dst) : "v"(off), "s"(preb))
// counted wait + fence (rule #18: reg-only consumers hoist past asm waits)
#define VMWAIT(N) do { asm volatile("s_waitcnt vmcnt(" #N ")" ::: "memory");      \
                       __builtin_amdgcn_sched_barrier(0); } while (0)
#define LAUNDER(x) asm volatile("" : "+v"(x))

// ---------------- per-edge MLP: MFMA layers 2+3, 64 edges/wave, ZERO LDS -----
__global__ void __launch_bounds__(256) edge_mlp(
    const uint16_t* __restrict__ pre,
    const int* __restrict__ src, const int* __restrict__ dst,
    const uint16_t* __restrict__ EFrag,
    const float* __restrict__ b2, const float* __restrict__ b3,
    float* __restrict__ out, long E)
{
    const int wave = threadIdx.x >> 6;
    const int lane = threadIdx.x & 63;
    const int m15  = lane & 15;      // compute-side: edge-in-subtile
    const int quad = lane >> 4;      // compute-side: k-chunk group
    const int em   = lane >> 2;      // gather-side: edge-in-subtile (0..15)
    const int ch4  = lane & 3;       // gather-side: 16B chunk in 64B line

    const long e0 = (long)(blockIdx.x * 4 + wave) * 64;
    if (e0 >= E) return;

    // ---- C++-visible loads: indices -> offsets, weight frags, biases --------
    uint32_t oa[4], ob[4];
#pragma unroll
    for (int st = 0; st < 4; st++) {
        long e = e0 + st * 16 + em;
        if (e >= E) e = E - 1;                       // stores guarded below
        oa[st] = (uint32_t)src[e] * 256u + (uint32_t)ch4 * 16u;
        ob[st] = (uint32_t)dst[e] * 256u + 128u + (uint32_t)ch4 * 16u;
    }
    bf16x8 bL2[4], bL3;
#pragma unroll
    for (int f = 0; f < 4; f++) bL2[f] = *(const bf16x8*)(EFrag + (f * 64 + lane) * 8);
    bL3 = *(const bf16x8*)(EFrag + (4 * 64 + lane) * 8);
    float4 t2a = *(const float4*)(b2 + quad * 4);
    float4 t2b = *(const float4*)(b2 + 16 + quad * 4);
    float ba0 = t2a.x, ba1 = t2a.y, ba2 = t2a.z, ba3 = t2a.w;
    float bb0 = t2b.x, bb1 = t2b.y, bb2 = t2b.z, bb3 = t2b.w;
    float vb3 = (m15 < 6) ? b3[m15] : 0.f;

    // Launder load results: breaks load->use provenance so the compiler's
    // waitcnt pass settles all C++ loads HERE, not inside the asm pipeline.
    LAUNDER(bL2[0]); LAUNDER(bL2[1]); LAUNDER(bL2[2]); LAUNDER(bL2[3]); LAUNDER(bL3);
    LAUNDER(ba0); LAUNDER(ba1); LAUNDER(ba2); LAUNDER(ba3);
    LAUNDER(bb0); LAUNDER(bb1); LAUNDER(bb2); LAUNDER(bb3); LAUNDER(vb3);
    asm volatile("s_waitcnt vmcnt(0)" ::: "memory");   // clean vmcnt baseline
    __builtin_amdgcn_sched_barrier(0);

    const char* preb = (const char*)pre;
    // bpermute source-lane byte addrs:
    //  repack (gather order -> A-frag): target (q,m) pulls from lane 4m+q.
    const int bp = ((m15 << 2) | quad) << 2;
    //  layer-3 (pk -> A3-frag): target (q,m) pulls from lanes (q&1)*32+m15 (+16).
    const int addrA = (((quad & 1) << 5) | m15) << 2;
    const int addrB = addrA + 64;
    const bool hiNT = (quad >= 2);

    u32x4 s0g0, s0g1, s0g2, s0g3, s1g0, s1g1, s1g2, s1g3;
    u32x4 s2g0, s2g1, s2g2, s2g3, s3g0, s3g1, s3g2, s3g3;

#define ISSUE(ST)                                                                 \
    GLOAD  (s##ST##g0, oa[ST]);   /* src chans  8*ch4.., line 0 */                \
    GLOAD64(s##ST##g1, oa[ST]);   /* src chans 32+8*ch4, line 1 */                \
    GLOAD  (s##ST##g2, ob[ST]);   /* dst chans 64+8*ch4, line 0 */                \
    GLOAD64(s##ST##g3, ob[ST]);   /* dst chans 96+8*ch4, line 1 */

    // ---- per subtile: relu2 (gather order) -> bpermute repack -> layer2 MFMA
    //      -> bpermute redistribution -> layer3 MFMA -> store ------------------
#define COMPUTE(ST)                                                               \
    {                                                                             \
        u32x4 Y0, Y1;                                                             \
        Y0.x = bfadd2_relu(s##ST##g0.x, s##ST##g2.x);                             \
        Y0.y = bfadd2_relu(s##ST##g0.y, s##ST##g2.y);                             \
        Y0.z = bfadd2_relu(s##ST##g0.z, s##ST##g2.z);                             \
        Y0.w = bfadd2_relu(s##ST##g0.w, s##ST##g2.w);                             \
        Y1.x = bfadd2_relu(s##ST##g1.x, s##ST##g3.x);                             \
        Y1.y = bfadd2_relu(s##ST##g1.y, s##ST##g3.y);                             \
        Y1.z = bfadd2_relu(s##ST##g1.z, s##ST##g3.z);                             \
        Y1.w = bfadd2_relu(s##ST##g1.w, s##ST##g3.w);                             \
        union { bf16x8 v; int u[4]; } A0, A1;                                     \
        A0.u[0] = __builtin_amdgcn_ds_bpermute(bp, (int)Y0.x);                    \
        A0.u[1] = __builtin_amdgcn_ds_bpermute(bp, (int)Y0.y);                    \
        A0.u[2] = __builtin_amdgcn_ds_bpermute(bp, (int)Y0.z);                    \
        A0.u[3] = __builtin_amdgcn_ds_bpermute(bp, (int)Y0.w);                    \
        A1.u[0] = __builtin_amdgcn_ds_bpermute(bp, (int)Y1.x);                    \
        A1.u[1] = __builtin_amdgcn_ds_bpermute(bp, (int)Y1.y);                    \
        A1.u[2] = __builtin_amdgcn_ds_bpermute(bp, (int)Y1.z);                    \
        A1.u[3] = __builtin_amdgcn_ds_bpermute(bp, (int)Y1.w);                    \
        uint32_t pk00, pk01, pk10, pk11;                                          \
        {                                                                         \
            f32x4 acc = {0.f, 0.f, 0.f, 0.f};                                     \
            acc = __builtin_amdgcn_mfma_f32_16x16x32_bf16(bL2[0], A0.v, acc, 0, 0, 0); \
            acc = __builtin_amdgcn_mfma_f32_16x16x32_bf16(bL2[2], A1.v, acc, 0, 0, 0); \
            pk00 = cvtpk(fmaxf(acc[0] + ba0, 0.f), fmaxf(acc[1] + ba1, 0.f));     \
            pk01 = cvtpk(fmaxf(acc[2] + ba2, 0.f), fmaxf(acc[3] + ba3, 0.f));     \
        }                                                                         \
        {                                                                         \
            f32x4 acc = {0.f, 0.f, 0.f, 0.f};                                     \
            acc = __builtin_amdgcn_mfma_f32_16x16x32_bf16(bL2[1], A0.v, acc, 0, 0, 0); \
            acc = __builtin_amdgcn_mfma_f32_16x16x32_bf16(bL2[3], A1.v, acc, 0, 0, 0); \
            pk10 = cvtpk(fmaxf(acc[0] + bb0, 0.f), fmaxf(acc[1] + bb1, 0.f));     \
            pk11 = cvtpk(fmaxf(acc[2] + bb2, 0.f), fmaxf(acc[3] + bb3, 0.f));     \
        }                                                                         \
        int d0n0 = __builtin_amdgcn_ds_bpermute(addrA, (int)pk00);                \
        int d1n0 = __builtin_amdgcn_ds_bpermute(addrA, (int)pk01);                \
        int d2n0 = __builtin_amdgcn_ds_bpermute(addrB, (int)pk00);                \
        int d3n0 = __builtin_amdgcn_ds_bpermute(addrB, (int)pk01);                \
        int d0n1 = __builtin_amdgcn_ds_bpermute(addrA, (int)pk10);                \
        int d1n1 = __builtin_amdgcn_ds_bpermute(addrA, (int)pk11);                \
        int d2n1 = __builtin_amdgcn_ds_bpermute(addrB, (int)pk10);                \
        int d3n1 = __builtin_amdgcn_ds_bpermute(addrB, (int)pk11);                \
        union { bf16x8 v; int u[4]; } A3;                                         \
        A3.u[0] = hiNT ? d0n1 : d0n0;                                             \
        A3.u[1] = hiNT ? d1n1 : d1n0;                                             \
        A3.u[2] = hiNT ? d2n1 : d2n0;                                             \
        A3.u[3] = hiNT ? d3n1 : d3n0;                                             \
        f32x4 o = {0.f, 0.f, 0.f, 0.f};                                           \
        o = __builtin_amdgcn_mfma_f32_16x16x32_bf16(A3.v, bL3, o, 0, 0, 0);       \
        if (m15 < 6) {                                                            \
            _Pragma("unroll")                                                     \
            for (int r = 0; r < 4; r++) {                                         \
                long e = e0 + (ST) * 16 + quad * 4 + r;                           \
                if (e < E) out[e * 6 + m15] = o[r] + vb3;                         \
            }                                                                     \
        }                                                                         \
    }

    // ---- depth-2 pipeline, hand-counted vmcnt -------------------------------
    ISSUE(0) ISSUE(1)            // 8 outstanding
    ISSUE(2)                     // 12 outstanding
    VMWAIT(8);  COMPUTE(0)       // subtile-0 loads retired
    ISSUE(3)                     // <=12 outstanding
    VMWAIT(8);  COMPUTE(1)       // subtile-1 retired
    VMWAIT(4);  COMPUTE(2)       // subtile-2 retired
    VMWAIT(0);  COMPUTE(3)
#undef ISSUE
#undef COMPUTE
}

extern "C" void kernel_launch(void* const* d_in, const int* in_sizes, int n_in,
                              void* d_out, int out_size, void* d_ws, size_t ws_size,
                              hipStream_t stream) {
    const float* h   = (const float*)d_in[0];
    const int*   src = (const int*)d_in[1];
    const int*   dst = (const int*)d_in[2];
    const float* W1  = (const float*)d_in[3];
    const float* b1  = (const float*)d_in[4];
    const float* W2  = (const float*)d_in[5];
    const float* b2  = (const float*)d_in[6];
    const float* W3  = (const float*)d_in[7];
    const float* b3  = (const float*)d_in[8];

    const int  N = in_sizes[0] / H;     // 100000
    const long E = in_sizes[1];         // 1600000

    char* ws = (char*)d_ws;
    uint16_t* Bfrag = (uint16_t*)ws;                 // 32 KiB
    uint16_t* EFrag = (uint16_t*)(ws + 64 * 1024);   // 5 KiB
    uint16_t* pre   = (uint16_t*)(ws + 128 * 1024);  // N*128*2 = 25.6 MB (bf16)

    prep_weights<<<64, 256, 0, stream>>>(W1, W2, W3, Bfrag, EFrag);
    node_gemm<<<(N + 127) / 128, 256, 0, stream>>>(h, Bfrag, b1, pre, N);
    const int eblocks = (int)((E + 255) / 256);      // 4 waves x 64 edges per block
    edge_mlp<<<eblocks, 256, 0, stream>>>(pre, src, dst, EFrag, b2, b3,
                                          (float*)d_out, E);
}